// Round 5
// baseline (277.835 us; speedup 1.0000x reference)
//
#include <hip/hip_runtime.h>
#include <hip/hip_bf16.h>
#include <stdint.h>
#include <stddef.h>

#define EMB 768
#define FFD 3072
#define NHEAD 12
#define HD 64
#define SEQ 1024
#define NTOK 8192
#define QKVW 2304

typedef unsigned short u16;
typedef __attribute__((ext_vector_type(8))) short short8;
typedef __attribute__((ext_vector_type(4))) float f32x4;

__device__ __forceinline__ u16 f2bf(float f) {
  union { float f; uint32_t u; } w; w.f = f;
  uint32_t x = w.u + 0x7fffu + ((w.u >> 16) & 1u);
  return (u16)(x >> 16);
}

__device__ __forceinline__ uint32_t pkbf(float lo, float hi) {
  __hip_bfloat162 h = __float22bfloat162_rn(float2{lo, hi});
  union { __hip_bfloat162 h; uint32_t u; } cv; cv.h = h;
  return cv.u;
}

__device__ __forceinline__ void g2l16(const void* g, void* l) {
  __builtin_amdgcn_global_load_lds(
      (const __attribute__((address_space(1))) void*)g,
      (__attribute__((address_space(3))) void*)l, 16, 0, 0);
}

#define VMCNT(n) asm volatile("s_waitcnt vmcnt(" #n ")" ::: "memory")
#define LGKM0()  asm volatile("s_waitcnt lgkmcnt(0)" ::: "memory")

// ---------------- weight transpose: fp32 [K][N] -> bf16 [N][K] ----------------
__global__ __launch_bounds__(256)
void transpose_kernel(const float* __restrict__ in, u16* __restrict__ out, int K, int N) {
  __shared__ float tile[32][33];
  const int n0 = blockIdx.x * 32, k0 = blockIdx.y * 32;
  const int tx = threadIdx.x & 31;
  const int ty = threadIdx.x >> 5;
#pragma unroll
  for (int i = 0; i < 32; i += 8)
    tile[ty + i][tx] = in[(size_t)(k0 + ty + i) * N + n0 + tx];
  __syncthreads();
#pragma unroll
  for (int i = 0; i < 32; i += 8)
    out[(size_t)(n0 + ty + i) * K + k0 + tx] = f2bf(tile[tx][ty + i]);
}

// merged Wq/Wk/Wv transpose (768x768 each), z selects the source
__global__ __launch_bounds__(256)
void transpose_qkv_kernel(const float* __restrict__ Wq, const float* __restrict__ Wk,
                          const float* __restrict__ Wv, u16* __restrict__ out) {
  __shared__ float tile[32][33];
  const float* in = blockIdx.z == 0 ? Wq : (blockIdx.z == 1 ? Wk : Wv);
  u16* o = out + (size_t)blockIdx.z * EMB * EMB;
  const int n0 = blockIdx.x * 32, k0 = blockIdx.y * 32;
  const int tx = threadIdx.x & 31;
  const int ty = threadIdx.x >> 5;
#pragma unroll
  for (int i = 0; i < 32; i += 8)
    tile[ty + i][tx] = in[(size_t)(k0 + ty + i) * EMB + n0 + tx];
  __syncthreads();
#pragma unroll
  for (int i = 0; i < 32; i += 8)
    o[(size_t)(n0 + ty + i) * EMB + k0 + tx] = f2bf(tile[tx][ty + i]);
}

// ---------------- layernorm: fp32 row -> bf16 row ----------------
__global__ __launch_bounds__(256)
void ln_kernel(const float* __restrict__ x, const float* __restrict__ sc,
               const float* __restrict__ sh, u16* __restrict__ out) {
  const int row = blockIdx.x;
  const int tid = threadIdx.x;
  const float* xr = x + (size_t)row * EMB;
  float v0 = xr[tid], v1 = xr[tid + 256], v2 = xr[tid + 512];
  float s = v0 + v1 + v2;
  float ss = v0 * v0 + v1 * v1 + v2 * v2;
#pragma unroll
  for (int m = 1; m < 64; m <<= 1) { s += __shfl_xor(s, m, 64); ss += __shfl_xor(ss, m, 64); }
  __shared__ float red[8];
  const int wave = tid >> 6, lane = tid & 63;
  if (lane == 0) { red[wave] = s; red[wave + 4] = ss; }
  __syncthreads();
  s = red[0] + red[1] + red[2] + red[3];
  ss = red[4] + red[5] + red[6] + red[7];
  const float mean = s * (1.f / EMB);
  const float var = ss * (1.f / EMB) - mean * mean;
  const float inv = rsqrtf(var + 1e-5f);
  u16* orow = out + (size_t)row * EMB;
  orow[tid]       = f2bf((v0 - mean) * inv * sc[tid]       + sh[tid]);
  orow[tid + 256] = f2bf((v1 - mean) * inv * sc[tid + 256] + sh[tid + 256]);
  orow[tid + 512] = f2bf((v2 - mean) * inv * sc[tid + 512] + sh[tid + 512]);
}

// ---------------- 256x256 8-phase bf16 GEMM (T3+T4+T5) ----------------
// C[M,N] = A[M,K] @ BT[N,K]^T.  512 threads = 8 waves (2M x 4N), BK=64.
// LDS 128KB: A/B x 2 halves x 2 dbuf, each half 128x64 bf16 (16KB).
// A-half h = rows with bit6==h (i.e. {h*64..h*64+63} U {128+h*64..}),
// B-half h = rows with bit5==h. Phase (mh,nh) reads A-half mh + B-half nh.
// Stage order per tile: A0(P1), B0(P2), B1(P3), A1(P4); uniform vmcnt(4)
// lands each half one phase before first read. EPI 2: GELU->bf16.
// EPI 3: QKV split (cols<1536 row-major bf16; V cols transposed into vTp).
template <int EPI>
__global__ __launch_bounds__(512, 2)
void gemm256_kernel(const u16* __restrict__ A, const u16* __restrict__ BT,
                    void* __restrict__ Cp, const float* __restrict__ bias,
                    u16* __restrict__ vTp, int M, int N, int K) {
  __shared__ u16 sm[65536];  // [0,32768): A halves; [32768,65536): B halves

  const int nwg = gridDim.x * gridDim.y;
  const int orig = blockIdx.y * gridDim.x + blockIdx.x;
  const int swzb = (orig & 7) * (nwg >> 3) + (orig >> 3);
  const int m0 = (swzb / gridDim.x) * 256;
  const int n0 = (swzb % gridDim.x) * 256;

  const int tid = threadIdx.x;
  const int w = tid >> 6, lane = tid & 63;
  const int wm = w >> 2, wn = w & 3;
  const int r = lane & 15, g = lane >> 4;
  const int sr = tid >> 3;                 // 0..63 (block-wide staging row)
  const int scw = ((tid & 7) * 8) ^ ((sr & 7) << 3);  // pre-swizzled source col

  f32x4 acc[8][4] = {};

  const int NT = K >> 6;

  // stage A-half h of K-tile t into dbuf p (2 x g2l16 per thread)
  auto stageA = [&](int p, int h, int t) {
    u16* dst = sm + (p * 2 + h) * 8192 + (w * 8) * 64;
    const u16* src = A + (size_t)(m0 + h * 64 + sr) * K + t * 64 + scw;
    g2l16(src, dst);
    g2l16(src + (size_t)128 * K, dst + 4096);
  };
  auto stageB = [&](int p, int h, int t) {
    u16* dst = sm + 32768 + (p * 2 + h) * 8192 + (w * 8) * 64;
    const int gr0 = h * 32 + (sr >> 5) * 64 + (sr & 31);
    const u16* src = BT + (size_t)(n0 + gr0) * K + t * 64 + scw;
    g2l16(src, dst);
    g2l16(src + (size_t)128 * K, dst + 4096);
  };

  // ds_read the quadrant frags (A: local row wm*64+mi2*16+r; B: wn*32+nf2*16+r)
  auto lda = [&](int p, int mh, short8 af[2][4]) {
    const u16* base = sm + (p * 2 + mh) * 8192;
#pragma unroll
    for (int kk = 0; kk < 2; ++kk)
#pragma unroll
      for (int mi2 = 0; mi2 < 4; ++mi2) {
        const int lr = wm * 64 + mi2 * 16 + r;
        af[kk][mi2] = *(const short8*)(base + lr * 64 + ((kk * 32 + g * 8) ^ ((r & 7) << 3)));
      }
  };
  auto ldb = [&](int p, int nh, short8 bf[2][2]) {
    const u16* base = sm + 32768 + (p * 2 + nh) * 8192;
#pragma unroll
    for (int kk = 0; kk < 2; ++kk)
#pragma unroll
      for (int nf2 = 0; nf2 < 2; ++nf2) {
        const int lr = wn * 32 + nf2 * 16 + r;
        bf[kk][nf2] = *(const short8*)(base + lr * 64 + ((kk * 32 + g * 8) ^ ((r & 7) << 3)));
      }
  };
  auto mfma16 = [&](int mh, int nh, short8 af[2][4], short8 bf[2][2]) {
    __builtin_amdgcn_s_setprio(1);
#pragma unroll
    for (int kk = 0; kk < 2; ++kk)
#pragma unroll
      for (int mi2 = 0; mi2 < 4; ++mi2)
#pragma unroll
        for (int nf2 = 0; nf2 < 2; ++nf2)
          acc[mh * 4 + mi2][nh * 2 + nf2] = __builtin_amdgcn_mfma_f32_16x16x32_bf16(
              af[kk][mi2], bf[kk][nf2], acc[mh * 4 + mi2][nh * 2 + nf2], 0, 0, 0);
    __builtin_amdgcn_s_setprio(0);
  };

  // prologue: tile 0 into buf 0 (order A0,B0,B1,A1), land A0+B0
  stageA(0, 0, 0); stageB(0, 0, 0); stageB(0, 1, 0); stageA(0, 1, 0);
  VMCNT(4);
  __builtin_amdgcn_s_barrier();

  for (int t = 0; t < NT - 1; ++t) {
    const int p = t & 1;
    {  // P1: (0,0), stage A0 of t+1
      short8 af[2][4], bf[2][2];
      lda(p, 0, af); ldb(p, 0, bf);
      stageA(p ^ 1, 0, t + 1);
      VMCNT(4); __builtin_amdgcn_s_barrier();
      mfma16(0, 0, af, bf);
      LGKM0(); __builtin_amdgcn_s_barrier();
    }
    {  // P2: (0,1), stage B0 of t+1
      short8 af[2][4], bf[2][2];
      lda(p, 0, af); ldb(p, 1, bf);
      stageB(p ^ 1, 0, t + 1);
      VMCNT(4); __builtin_amdgcn_s_barrier();
      mfma16(0, 1, af, bf);
      LGKM0(); __builtin_amdgcn_s_barrier();
    }
    {  // P3: (1,0), stage B1 of t+1
      short8 af[2][4], bf[2][2];
      lda(p, 1, af); ldb(p, 0, bf);
      stageB(p ^ 1, 1, t + 1);
      VMCNT(4); __builtin_amdgcn_s_barrier();
      mfma16(1, 0, af, bf);
      LGKM0(); __builtin_amdgcn_s_barrier();
    }
    {  // P4: (1,1), stage A1 of t+1
      short8 af[2][4], bf[2][2];
      lda(p, 1, af); ldb(p, 1, bf);
      stageA(p ^ 1, 1, t + 1);
      VMCNT(4); __builtin_amdgcn_s_barrier();
      mfma16(1, 1, af, bf);
      LGKM0(); __builtin_amdgcn_s_barrier();
    }
  }
  {  // last tile: everything already issued; drain and compute
    const int p = (NT - 1) & 1;
    VMCNT(0);
    __builtin_amdgcn_s_barrier();
#pragma unroll
    for (int mh = 0; mh < 2; ++mh)
#pragma unroll
      for (int nh = 0; nh < 2; ++nh) {
        short8 af[2][4], bf[2][2];
        lda(p, mh, af); ldb(p, nh, bf);
        mfma16(mh, nh, af, bf);
      }
  }

  // epilogue
#pragma unroll
  for (int mi = 0; mi < 8; ++mi)
#pragma unroll
    for (int ni = 0; ni < 4; ++ni) {
      const int rowb = m0 + wm * 128 + mi * 16 + 4 * g;
      const int col = n0 + wn * 64 + ni * 16 + r;
      if constexpr (EPI == 3) {
        u16 pk[4];
#pragma unroll
        for (int j = 0; j < 4; ++j) pk[j] = f2bf(acc[mi][ni][j]);
        if (col < 1536) {
#pragma unroll
          for (int j = 0; j < 4; ++j)
            ((u16*)Cp)[(size_t)(rowb + j) * N + col] = pk[j];
        } else {
          uint2 w2;
          w2.x = (uint32_t)pk[0] | ((uint32_t)pk[1] << 16);
          w2.y = (uint32_t)pk[2] | ((uint32_t)pk[3] << 16);
          *(uint2*)(vTp + (size_t)(col - 1536) * NTOK + rowb) = w2;
        }
      } else {
#pragma unroll
        for (int j = 0; j < 4; ++j) {
          float t = acc[mi][ni][j] + bias[col];
          float e = __expf(1.5957691216057308f * (t + 0.044715f * t * t * t));
          float th = 1.f - 2.f / (e + 1.f);
          ((u16*)Cp)[(size_t)(rowb + j) * N + col] = f2bf(0.5f * t * (1.f + th));
        }
      }
    }
}

// ---------------- legacy 2-barrier GEMM (Wo / FF2, N=768) ----------------
// EPI 1: C f32 = acc + bias[n] + res[m*N+n]
template <int EPI, int MT>
__global__ __launch_bounds__(256)
void gemm_kernel(const u16* __restrict__ A, const u16* __restrict__ BT,
                 void* __restrict__ Cp, const float* __restrict__ bias,
                 const float* __restrict__ res, int M, int N, int K) {
  constexpr int MI = MT / 32;
  __shared__ u16 As[MT * 64];
  __shared__ u16 Bs[128 * 64];

  const int nwg = gridDim.x * gridDim.y;
  const int orig = blockIdx.y * gridDim.x + blockIdx.x;
  const int swz = (orig & 7) * (nwg >> 3) + (orig >> 3);
  const int m0 = (swz / gridDim.x) * MT;
  const int n0 = (swz % gridDim.x) * 128;

  const int tid = threadIdx.x;
  const int wave = tid >> 6, lane = tid & 63;
  const int wr = wave >> 1, wc = wave & 1;
  const int r = lane & 15, g = lane >> 4;
  const int lrow = lane >> 3;
  const int lelem = (lane & 7) * 8;

  f32x4 acc[MI][4] = {};

  const int nkt = K >> 6;
  for (int kt = 0; kt < nkt; ++kt) {
    const int k0 = kt << 6;
    if (kt) __syncthreads();
#pragma unroll
    for (int q = 0; q < MT / 32; ++q) {
      const int chunk = q * 4 + wave;
      const int row = chunk * 8 + lrow;
      const int e = lelem ^ ((row & 7) << 3);
      g2l16(A + (size_t)(m0 + row) * K + k0 + e, As + chunk * 512);
    }
#pragma unroll
    for (int q = 0; q < 4; ++q) {
      const int chunk = q * 4 + wave;
      const int row = chunk * 8 + lrow;
      const int e = lelem ^ ((row & 7) << 3);
      g2l16(BT + (size_t)(n0 + row) * K + k0 + e, Bs + chunk * 512);
    }
    __syncthreads();
#pragma unroll
    for (int kk = 0; kk < 2; ++kk) {
      short8 af[MI], bf[4];
#pragma unroll
      for (int mi = 0; mi < MI; ++mi) {
        const int row = wr * (MT / 2) + mi * 16 + r;
        af[mi] = *(const short8*)(As + row * 64 + ((kk * 32 + g * 8) ^ ((row & 7) << 3)));
      }
#pragma unroll
      for (int ni = 0; ni < 4; ++ni) {
        const int row = wc * 64 + ni * 16 + r;
        bf[ni] = *(const short8*)(Bs + row * 64 + ((kk * 32 + g * 8) ^ ((row & 7) << 3)));
      }
#pragma unroll
      for (int mi = 0; mi < MI; ++mi)
#pragma unroll
        for (int ni = 0; ni < 4; ++ni)
          acc[mi][ni] = __builtin_amdgcn_mfma_f32_16x16x32_bf16(af[mi], bf[ni], acc[mi][ni], 0, 0, 0);
    }
  }

#pragma unroll
  for (int mi = 0; mi < MI; ++mi)
#pragma unroll
    for (int ni = 0; ni < 4; ++ni)
#pragma unroll
      for (int j = 0; j < 4; ++j) {
        const int row = m0 + wr * (MT / 2) + mi * 16 + 4 * g + j;
        const int col = n0 + wc * 64 + ni * 16 + r;
        const size_t idx = (size_t)row * N + col;
        ((float*)Cp)[idx] = acc[mi][ni][j] + bias[col] + res[idx];
      }
}

// ---------------- flash attention, causal, QBLK=128, swapped-QK^T ----------------
#define CEXP 0.18033688011112042f  /* log2(e)/8 */

__global__ __launch_bounds__(256, 3)
void attn_kernel(const u16* __restrict__ qkv, const u16* __restrict__ vT,
                 u16* __restrict__ ctx) {
  const int bh = blockIdx.x;
  const int qt = blockIdx.y;
  const int b = bh / NHEAD, h = bh % NHEAD;
  const int tid = threadIdx.x;
  const int wave = tid >> 6, lane = tid & 63;
  const int r = lane & 15, g = lane >> 4;

  __shared__ u16 Kb[2][64 * 64];
  __shared__ u16 Vb[2][64 * 64];
  __shared__ u16 Pt[4][16 * 64];

  const int qw = qt * 128 + wave * 32;
  const int tok0 = b * SEQ;

  short8 aq[2][2];
#pragma unroll
  for (int qf = 0; qf < 2; ++qf) {
    const u16* qb = qkv + (size_t)(tok0 + qw + qf * 16 + r) * QKVW + h * HD;
    aq[qf][0] = *(const short8*)(qb + g * 8);
    aq[qf][1] = *(const short8*)(qb + 32 + g * 8);
  }

  float l_st[2] = {0.f, 0.f};
  f32x4 oc[2][4] = {};

  const int sr = tid >> 3;
  const int sc = (tid & 7) * 8;
  const int nt = 2 * qt + 2;

  const u16* kg = qkv + (size_t)tok0 * QKVW + EMB + h * HD;
  const u16* vg = vT + (size_t)(h * HD) * NTOK + tok0;
  const int e0 = sc ^ ((sr & 7) << 3);

  auto stage = [&](int buf, int kt) {
    const size_t koff = (size_t)kt * 64;
    u16* kb = (u16*)Kb[buf] + wave * 512;
    u16* vb = (u16*)Vb[buf] + wave * 512;
    g2l16(kg + (koff + sr) * QKVW + e0, kb);
    g2l16(kg + (koff + sr + 32) * QKVW + e0, kb + 2048);
    g2l16(vg + (size_t)sr * NTOK + koff + e0, vb);
    g2l16(vg + (size_t)(sr + 32) * NTOK + koff + e0, vb + 2048);
  };

  stage(0, 0);
  for (int kb = 0; kb < nt; ++kb) {
    __syncthreads();
    const int cur = kb & 1;
    if (kb + 1 < nt) stage(cur ^ 1, kb + 1);

    const int kv0 = kb * 64;
    if (kv0 > qw + 31) continue;

    short8 kf[4][2];
#pragma unroll
    for (int nf = 0; nf < 4; ++nf) {
      const int row = nf * 16 + r;
#pragma unroll
      for (int kk = 0; kk < 2; ++kk)
        kf[nf][kk] = *(const short8*)((char*)Kb[cur] + row * 128 +
                                      ((kk * 64 + g * 16) ^ ((row & 7) << 4)));
    }
    short8 bv[2][4];
#pragma unroll
    for (int half = 0; half < 2; ++half)
#pragma unroll
      for (int nd = 0; nd < 4; ++nd) {
        const int vr = nd * 16 + r;
        bv[half][nd] = *(const short8*)((char*)Vb[cur] + vr * 128 +
                       ((half * 64 + g * 16) ^ ((vr & 7) << 4)));
      }

#pragma unroll
    for (int qf = 0; qf < 2; ++qf) {
      f32x4 st[4];
#pragma unroll
      for (int nf = 0; nf < 4; ++nf) {
        f32x4 z = {};
        z = __builtin_amdgcn_mfma_f32_16x16x32_bf16(kf[nf][0], aq[qf][0], z, 0, 0, 0);
        z = __builtin_amdgcn_mfma_f32_16x16x32_bf16(kf[nf][1], aq[qf][1], z, 0, 0, 0);
        st[nf] = z;
      }
      if (kv0 + 63 > qw + qf * 16) {
        const int qg = qw + qf * 16 + r;
#pragma unroll
        for (int nf = 0; nf < 4; ++nf)
#pragma unroll
          for (int j = 0; j < 4; ++j)
            if (kv0 + nf * 16 + 4 * g + j > qg) st[nf][j] = -3e38f;
      }
      float p[4][4];
      float ps = 0.f;
#pragma unroll
      for (int nf = 0; nf < 4; ++nf)
#pragma unroll
        for (int j = 0; j < 4; ++j) {
          const float pe = exp2f(st[nf][j] * CEXP);
          p[nf][j] = pe;
          ps += pe;
        }
      ps += __shfl_xor(ps, 16);
      ps += __shfl_xor(ps, 32);
      l_st[qf] += ps;

      u16* Pw = (u16*)Pt[wave];
#pragma unroll
      for (int nf = 0; nf < 4; ++nf) {
        uint2 w2;
        w2.x = pkbf(p[nf][0], p[nf][1]);
        w2.y = pkbf(p[nf][2], p[nf][3]);
        *(uint2*)((char*)Pw + r * 128 + ((nf * 32 + g * 8) ^ ((r & 7) << 4))) = w2;
      }
#pragma unroll
      for (int half = 0; half < 2; ++half) {
        short8 pa = *(const short8*)((char*)Pw + r * 128 +
                                     ((half * 64 + g * 16) ^ ((r & 7) << 4)));
#pragma unroll
        for (int nd = 0; nd < 4; ++nd)
          oc[qf][nd] = __builtin_amdgcn_mfma_f32_16x16x32_bf16(pa, bv[half][nd], oc[qf][nd], 0, 0, 0);
      }
    }
  }

#pragma unroll
  for (int qf = 0; qf < 2; ++qf) {
    const float rl = 1.f / l_st[qf];
#pragma unroll
    for (int j = 0; j < 4; ++j) {
      const float rj = __shfl(rl, 4 * g + j, 16);
      const size_t row = (size_t)tok0 + qw + qf * 16 + 4 * g + j;
#pragma unroll
      for (int nd = 0; nd < 4; ++nd)
        ctx[row * EMB + h * HD + nd * 16 + r] = f2bf(oc[qf][nd][j] * rj);
    }
  }
}

extern "C" void kernel_launch(void* const* d_in, const int* in_sizes, int n_in,
                              void* d_out, int out_size, void* d_ws, size_t ws_size,
                              hipStream_t stream) {
  const float* x    = (const float*)d_in[0];
  const float* Wq   = (const float*)d_in[1];
  const float* Wk   = (const float*)d_in[2];
  const float* Wv   = (const float*)d_in[3];
  const float* Wo   = (const float*)d_in[4];
  const float* bo   = (const float*)d_in[5];
  const float* W1   = (const float*)d_in[6];
  const float* b1   = (const float*)d_in[7];
  const float* W2   = (const float*)d_in[8];
  const float* b2   = (const float*)d_in[9];
  const float* ln1s = (const float*)d_in[10];
  const float* ln1b = (const float*)d_in[11];
  const float* ln2s = (const float*)d_in[12];
  const float* ln2b = (const float*)d_in[13];

  char* p = (char*)d_ws;
  u16* qkvT = (u16*)p; p += (size_t)QKVW * EMB * 2;
  u16* woT  = (u16*)p; p += (size_t)EMB * EMB * 2;
  u16* w1T  = (u16*)p; p += (size_t)FFD * EMB * 2;
  u16* w2T  = (u16*)p; p += (size_t)EMB * FFD * 2;
  u16* h1   = (u16*)p; p += (size_t)NTOK * EMB * 2;
  u16* qkv  = (u16*)p; p += (size_t)NTOK * QKVW * 2;
  float* x2 = (float*)p; p += (size_t)NTOK * EMB * 4;
  u16* ff1  = (u16*)p; p += (size_t)NTOK * FFD * 2;
  u16* ctxb = h1;        // h1 dead after QKV GEMM
  u16* h2   = qkv;       // qkv dead after attention
  u16* vT   = ff1;       // vT lives [QKV GEMM, attn); ff1 lives [FF1 GEMM, end)

  if (ws_size < (size_t)(p - (char*)d_ws)) return;

  dim3 blk(256);
  transpose_qkv_kernel<<<dim3(24, 24, 3), blk, 0, stream>>>(Wq, Wk, Wv, qkvT);
  transpose_kernel<<<dim3(24, 24), blk, 0, stream>>>(Wo, woT, EMB, EMB);
  transpose_kernel<<<dim3(96, 24), blk, 0, stream>>>(W1, w1T, EMB, FFD);
  transpose_kernel<<<dim3(24, 96), blk, 0, stream>>>(W2, w2T, FFD, EMB);

  ln_kernel<<<NTOK, blk, 0, stream>>>(x, ln1s, ln1b, h1);
  gemm256_kernel<3><<<dim3(9, 32), dim3(512), 0, stream>>>(h1, qkvT, qkv, nullptr, vT, NTOK, QKVW, EMB);
  attn_kernel<<<dim3(96, 8), blk, 0, stream>>>(qkv, vT, ctxb);
  gemm_kernel<1, 64><<<dim3(6, 128), blk, 0, stream>>>(ctxb, woT, x2, bo, x, NTOK, EMB, EMB);
  ln_kernel<<<NTOK, blk, 0, stream>>>(x2, ln2s, ln2b, h2);
  gemm256_kernel<2><<<dim3(12, 32), dim3(512), 0, stream>>>(h2, w1T, ff1, b1, nullptr, NTOK, FFD, EMB);
  gemm_kernel<1, 64><<<dim3(6, 128), blk, 0, stream>>>(ff1, w2T, (float*)d_out, b2, x2, NTOK, EMB, FFD);
}

// Round 6
// 249.633 us; speedup vs baseline: 1.1130x; 1.1130x over previous
//
#include <hip/hip_runtime.h>
#include <hip/hip_bf16.h>
#include <stdint.h>
#include <stddef.h>

#define EMB 768
#define FFD 3072
#define NHEAD 12
#define HD 64
#define SEQ 1024
#define NTOK 8192
#define QKVW 2304

typedef unsigned short u16;
typedef __attribute__((ext_vector_type(8))) short short8;
typedef __attribute__((ext_vector_type(4))) float f32x4;

__device__ __forceinline__ u16 f2bf(float f) {
  union { float f; uint32_t u; } w; w.f = f;
  uint32_t x = w.u + 0x7fffu + ((w.u >> 16) & 1u);
  return (u16)(x >> 16);
}

__device__ __forceinline__ uint32_t pkbf(float lo, float hi) {
  __hip_bfloat162 h = __float22bfloat162_rn(float2{lo, hi});
  union { __hip_bfloat162 h; uint32_t u; } cv; cv.h = h;
  return cv.u;
}

__device__ __forceinline__ void g2l16(const void* g, void* l) {
  __builtin_amdgcn_global_load_lds(
      (const __attribute__((address_space(1))) void*)g,
      (__attribute__((address_space(3))) void*)l, 16, 0, 0);
}

// ---------------- weight transpose: fp32 [K][N] -> bf16 [N][K] ----------------
__global__ __launch_bounds__(256)
void transpose_kernel(const float* __restrict__ in, u16* __restrict__ out, int K, int N) {
  __shared__ float tile[32][33];
  const int n0 = blockIdx.x * 32, k0 = blockIdx.y * 32;
  const int tx = threadIdx.x & 31;
  const int ty = threadIdx.x >> 5;
#pragma unroll
  for (int i = 0; i < 32; i += 8)
    tile[ty + i][tx] = in[(size_t)(k0 + ty + i) * N + n0 + tx];
  __syncthreads();
#pragma unroll
  for (int i = 0; i < 32; i += 8)
    out[(size_t)(n0 + ty + i) * K + k0 + tx] = f2bf(tile[tx][ty + i]);
}

// merged Wq/Wk/Wv transpose (768x768 each), z selects the source
__global__ __launch_bounds__(256)
void transpose_qkv_kernel(const float* __restrict__ Wq, const float* __restrict__ Wk,
                          const float* __restrict__ Wv, u16* __restrict__ out) {
  __shared__ float tile[32][33];
  const float* in = blockIdx.z == 0 ? Wq : (blockIdx.z == 1 ? Wk : Wv);
  u16* o = out + (size_t)blockIdx.z * EMB * EMB;
  const int n0 = blockIdx.x * 32, k0 = blockIdx.y * 32;
  const int tx = threadIdx.x & 31;
  const int ty = threadIdx.x >> 5;
#pragma unroll
  for (int i = 0; i < 32; i += 8)
    tile[ty + i][tx] = in[(size_t)(k0 + ty + i) * EMB + n0 + tx];
  __syncthreads();
#pragma unroll
  for (int i = 0; i < 32; i += 8)
    o[(size_t)(n0 + ty + i) * EMB + k0 + tx] = f2bf(tile[tx][ty + i]);
}

// ---------------- layernorm: fp32 row -> bf16 row ----------------
__global__ __launch_bounds__(256)
void ln_kernel(const float* __restrict__ x, const float* __restrict__ sc,
               const float* __restrict__ sh, u16* __restrict__ out) {
  const int row = blockIdx.x;
  const int tid = threadIdx.x;
  const float* xr = x + (size_t)row * EMB;
  float v0 = xr[tid], v1 = xr[tid + 256], v2 = xr[tid + 512];
  float s = v0 + v1 + v2;
  float ss = v0 * v0 + v1 * v1 + v2 * v2;
#pragma unroll
  for (int m = 1; m < 64; m <<= 1) { s += __shfl_xor(s, m, 64); ss += __shfl_xor(ss, m, 64); }
  __shared__ float red[8];
  const int wave = tid >> 6, lane = tid & 63;
  if (lane == 0) { red[wave] = s; red[wave + 4] = ss; }
  __syncthreads();
  s = red[0] + red[1] + red[2] + red[3];
  ss = red[4] + red[5] + red[6] + red[7];
  const float mean = s * (1.f / EMB);
  const float var = ss * (1.f / EMB) - mean * mean;
  const float inv = rsqrtf(var + 1e-5f);
  u16* orow = out + (size_t)row * EMB;
  orow[tid]       = f2bf((v0 - mean) * inv * sc[tid]       + sh[tid]);
  orow[tid + 256] = f2bf((v1 - mean) * inv * sc[tid + 256] + sh[tid + 256]);
  orow[tid + 512] = f2bf((v2 - mean) * inv * sc[tid + 512] + sh[tid + 512]);
}

// ---------------- bf16 GEMM, 2-phase double-buffered (T3-min) ----------------
// C[M,N] = A[M,K] @ BT[N,K]^T.  Tile MT x 128, BK=64, 4 waves (2x2).
// Loop: barrier -> stage(tile t+1 -> buf^1) -> ds_read+MFMA(buf).
// One barrier/tile; g2l latency hides under the full compute phase
// (same structure as attn_kernel, which profiles well).
// EPI 1: C f32  = acc + bias[n] + res[m*N+n]
// EPI 2: C bf16 = gelu_tanh(acc + bias[n])
// EPI 3: QKV split (cols<1536 row-major bf16; V cols transposed into vTp)
template <int EPI, int MT>
__global__ __launch_bounds__(256)
void gemm_kernel(const u16* __restrict__ A, const u16* __restrict__ BT,
                 void* __restrict__ Cp, const float* __restrict__ bias,
                 const float* __restrict__ res, u16* __restrict__ vTp,
                 int M, int N, int K) {
  constexpr int MI = MT / 32;
  __shared__ u16 As[2][MT * 64];
  __shared__ u16 Bs[2][128 * 64];

  const int nwg = gridDim.x * gridDim.y;
  const int orig = blockIdx.y * gridDim.x + blockIdx.x;
  const int swz = (orig & 7) * (nwg >> 3) + (orig >> 3);
  const int m0 = (swz / gridDim.x) * MT;
  const int n0 = (swz % gridDim.x) * 128;

  const int tid = threadIdx.x;
  const int wave = tid >> 6, lane = tid & 63;
  const int wr = wave >> 1, wc = wave & 1;
  const int r = lane & 15, g = lane >> 4;
  const int lrow = lane >> 3;
  const int lelem = (lane & 7) * 8;

  f32x4 acc[MI][4] = {};

  // stage K-tile kt into dbuf `buf` (A: MT/32 chunks, B: 4 chunks per thread)
  auto stage = [&](int buf, int kt) {
    const int k0 = kt << 6;
#pragma unroll
    for (int q = 0; q < MT / 32; ++q) {
      const int chunk = q * 4 + wave;
      const int row = chunk * 8 + lrow;
      const int e = lelem ^ ((row & 7) << 3);
      g2l16(A + (size_t)(m0 + row) * K + k0 + e, (u16*)As[buf] + chunk * 512);
    }
#pragma unroll
    for (int q = 0; q < 4; ++q) {
      const int chunk = q * 4 + wave;
      const int row = chunk * 8 + lrow;
      const int e = lelem ^ ((row & 7) << 3);
      g2l16(BT + (size_t)(n0 + row) * K + k0 + e, (u16*)Bs[buf] + chunk * 512);
    }
  };

  const int nkt = K >> 6;
  stage(0, 0);
  for (int kt = 0; kt < nkt; ++kt) {
    __syncthreads();  // implicit vmcnt(0) drains buf[cur]'s loads; protects buf[cur^1] overwrite
    const int cur = kt & 1;
    if (kt + 1 < nkt) stage(cur ^ 1, kt + 1);
    const u16* ab = (const u16*)As[cur];
    const u16* bb = (const u16*)Bs[cur];
#pragma unroll
    for (int kk = 0; kk < 2; ++kk) {
      short8 af[MI], bf[4];
#pragma unroll
      for (int mi = 0; mi < MI; ++mi) {
        const int row = wr * (MT / 2) + mi * 16 + r;
        af[mi] = *(const short8*)(ab + row * 64 + ((kk * 32 + g * 8) ^ ((row & 7) << 3)));
      }
#pragma unroll
      for (int ni = 0; ni < 4; ++ni) {
        const int row = wc * 64 + ni * 16 + r;
        bf[ni] = *(const short8*)(bb + row * 64 + ((kk * 32 + g * 8) ^ ((row & 7) << 3)));
      }
#pragma unroll
      for (int mi = 0; mi < MI; ++mi)
#pragma unroll
        for (int ni = 0; ni < 4; ++ni)
          acc[mi][ni] = __builtin_amdgcn_mfma_f32_16x16x32_bf16(af[mi], bf[ni], acc[mi][ni], 0, 0, 0);
    }
  }

#pragma unroll
  for (int mi = 0; mi < MI; ++mi)
#pragma unroll
    for (int ni = 0; ni < 4; ++ni) {
      const int rowb = m0 + wr * (MT / 2) + mi * 16 + 4 * g;
      const int col = n0 + wc * 64 + ni * 16 + r;
      if constexpr (EPI == 3) {
        u16 pk[4];
#pragma unroll
        for (int j = 0; j < 4; ++j) pk[j] = f2bf(acc[mi][ni][j]);
        if (col < 1536) {
#pragma unroll
          for (int j = 0; j < 4; ++j)
            ((u16*)Cp)[(size_t)(rowb + j) * N + col] = pk[j];
        } else {
          uint2 w2;
          w2.x = (uint32_t)pk[0] | ((uint32_t)pk[1] << 16);
          w2.y = (uint32_t)pk[2] | ((uint32_t)pk[3] << 16);
          *(uint2*)(vTp + (size_t)(col - 1536) * NTOK + rowb) = w2;
        }
      } else {
#pragma unroll
        for (int j = 0; j < 4; ++j) {
          const size_t idx = (size_t)(rowb + j) * N + col;
          float v = acc[mi][ni][j];
          if constexpr (EPI == 1) {
            ((float*)Cp)[idx] = v + bias[col] + res[idx];
          } else {
            float t = v + bias[col];
            float e = __expf(1.5957691216057308f * (t + 0.044715f * t * t * t));
            float th = 1.f - 2.f / (e + 1.f);
            ((u16*)Cp)[idx] = f2bf(0.5f * t * (1.f + th));
          }
        }
      }
    }
}

// ---------------- flash attention, causal, QBLK=128, swapped-QK^T ----------------
#define CEXP 0.18033688011112042f  /* log2(e)/8 */

__global__ __launch_bounds__(256, 3)
void attn_kernel(const u16* __restrict__ qkv, const u16* __restrict__ vT,
                 u16* __restrict__ ctx) {
  const int bh = blockIdx.x;
  const int qt = blockIdx.y;
  const int b = bh / NHEAD, h = bh % NHEAD;
  const int tid = threadIdx.x;
  const int wave = tid >> 6, lane = tid & 63;
  const int r = lane & 15, g = lane >> 4;

  __shared__ u16 Kb[2][64 * 64];
  __shared__ u16 Vb[2][64 * 64];
  __shared__ u16 Pt[4][16 * 64];

  const int qw = qt * 128 + wave * 32;
  const int tok0 = b * SEQ;

  short8 aq[2][2];
#pragma unroll
  for (int qf = 0; qf < 2; ++qf) {
    const u16* qb = qkv + (size_t)(tok0 + qw + qf * 16 + r) * QKVW + h * HD;
    aq[qf][0] = *(const short8*)(qb + g * 8);
    aq[qf][1] = *(const short8*)(qb + 32 + g * 8);
  }

  float l_st[2] = {0.f, 0.f};
  f32x4 oc[2][4] = {};

  const int sr = tid >> 3;
  const int sc = (tid & 7) * 8;
  const int nt = 2 * qt + 2;

  const u16* kg = qkv + (size_t)tok0 * QKVW + EMB + h * HD;
  const u16* vg = vT + (size_t)(h * HD) * NTOK + tok0;
  const int e0 = sc ^ ((sr & 7) << 3);

  auto stage = [&](int buf, int kt) {
    const size_t koff = (size_t)kt * 64;
    u16* kb = (u16*)Kb[buf] + wave * 512;
    u16* vb = (u16*)Vb[buf] + wave * 512;
    g2l16(kg + (koff + sr) * QKVW + e0, kb);
    g2l16(kg + (koff + sr + 32) * QKVW + e0, kb + 2048);
    g2l16(vg + (size_t)sr * NTOK + koff + e0, vb);
    g2l16(vg + (size_t)(sr + 32) * NTOK + koff + e0, vb + 2048);
  };

  stage(0, 0);
  for (int kb = 0; kb < nt; ++kb) {
    __syncthreads();
    const int cur = kb & 1;
    if (kb + 1 < nt) stage(cur ^ 1, kb + 1);

    const int kv0 = kb * 64;
    if (kv0 > qw + 31) continue;

    short8 kf[4][2];
#pragma unroll
    for (int nf = 0; nf < 4; ++nf) {
      const int row = nf * 16 + r;
#pragma unroll
      for (int kk = 0; kk < 2; ++kk)
        kf[nf][kk] = *(const short8*)((char*)Kb[cur] + row * 128 +
                                      ((kk * 64 + g * 16) ^ ((row & 7) << 4)));
    }
    short8 bv[2][4];
#pragma unroll
    for (int half = 0; half < 2; ++half)
#pragma unroll
      for (int nd = 0; nd < 4; ++nd) {
        const int vr = nd * 16 + r;
        bv[half][nd] = *(const short8*)((char*)Vb[cur] + vr * 128 +
                       ((half * 64 + g * 16) ^ ((vr & 7) << 4)));
      }

#pragma unroll
    for (int qf = 0; qf < 2; ++qf) {
      f32x4 st[4];
#pragma unroll
      for (int nf = 0; nf < 4; ++nf) {
        f32x4 z = {};
        z = __builtin_amdgcn_mfma_f32_16x16x32_bf16(kf[nf][0], aq[qf][0], z, 0, 0, 0);
        z = __builtin_amdgcn_mfma_f32_16x16x32_bf16(kf[nf][1], aq[qf][1], z, 0, 0, 0);
        st[nf] = z;
      }
      if (kv0 + 63 > qw + qf * 16) {
        const int qg = qw + qf * 16 + r;
#pragma unroll
        for (int nf = 0; nf < 4; ++nf)
#pragma unroll
          for (int j = 0; j < 4; ++j)
            if (kv0 + nf * 16 + 4 * g + j > qg) st[nf][j] = -3e38f;
      }
      float p[4][4];
      float ps = 0.f;
#pragma unroll
      for (int nf = 0; nf < 4; ++nf)
#pragma unroll
        for (int j = 0; j < 4; ++j) {
          const float pe = exp2f(st[nf][j] * CEXP);
          p[nf][j] = pe;
          ps += pe;
        }
      ps += __shfl_xor(ps, 16);
      ps += __shfl_xor(ps, 32);
      l_st[qf] += ps;

      u16* Pw = (u16*)Pt[wave];
#pragma unroll
      for (int nf = 0; nf < 4; ++nf) {
        uint2 w2;
        w2.x = pkbf(p[nf][0], p[nf][1]);
        w2.y = pkbf(p[nf][2], p[nf][3]);
        *(uint2*)((char*)Pw + r * 128 + ((nf * 32 + g * 8) ^ ((r & 7) << 4))) = w2;
      }
#pragma unroll
      for (int half = 0; half < 2; ++half) {
        short8 pa = *(const short8*)((char*)Pw + r * 128 +
                                     ((half * 64 + g * 16) ^ ((r & 7) << 4)));
#pragma unroll
        for (int nd = 0; nd < 4; ++nd)
          oc[qf][nd] = __builtin_amdgcn_mfma_f32_16x16x32_bf16(pa, bv[half][nd], oc[qf][nd], 0, 0, 0);
      }
    }
  }

#pragma unroll
  for (int qf = 0; qf < 2; ++qf) {
    const float rl = 1.f / l_st[qf];
#pragma unroll
    for (int j = 0; j < 4; ++j) {
      const float rj = __shfl(rl, 4 * g + j, 16);
      const size_t row = (size_t)tok0 + qw + qf * 16 + 4 * g + j;
#pragma unroll
      for (int nd = 0; nd < 4; ++nd)
        ctx[row * EMB + h * HD + nd * 16 + r] = f2bf(oc[qf][nd][j] * rj);
    }
  }
}

extern "C" void kernel_launch(void* const* d_in, const int* in_sizes, int n_in,
                              void* d_out, int out_size, void* d_ws, size_t ws_size,
                              hipStream_t stream) {
  const float* x    = (const float*)d_in[0];
  const float* Wq   = (const float*)d_in[1];
  const float* Wk   = (const float*)d_in[2];
  const float* Wv   = (const float*)d_in[3];
  const float* Wo   = (const float*)d_in[4];
  const float* bo   = (const float*)d_in[5];
  const float* W1   = (const float*)d_in[6];
  const float* b1   = (const float*)d_in[7];
  const float* W2   = (const float*)d_in[8];
  const float* b2   = (const float*)d_in[9];
  const float* ln1s = (const float*)d_in[10];
  const float* ln1b = (const float*)d_in[11];
  const float* ln2s = (const float*)d_in[12];
  const float* ln2b = (const float*)d_in[13];

  char* p = (char*)d_ws;
  u16* qkvT = (u16*)p; p += (size_t)QKVW * EMB * 2;
  u16* woT  = (u16*)p; p += (size_t)EMB * EMB * 2;
  u16* w1T  = (u16*)p; p += (size_t)FFD * EMB * 2;
  u16* w2T  = (u16*)p; p += (size_t)EMB * FFD * 2;
  u16* h1   = (u16*)p; p += (size_t)NTOK * EMB * 2;
  u16* qkv  = (u16*)p; p += (size_t)NTOK * QKVW * 2;
  float* x2 = (float*)p; p += (size_t)NTOK * EMB * 4;
  u16* ff1  = (u16*)p; p += (size_t)NTOK * FFD * 2;
  u16* ctxb = h1;        // h1 dead after QKV GEMM
  u16* h2   = qkv;       // qkv dead after attention
  u16* vT   = ff1;       // vT lives [QKV GEMM, attn); ff1 lives [FF1 GEMM, end)

  if (ws_size < (size_t)(p - (char*)d_ws)) return;

  dim3 blk(256);
  transpose_qkv_kernel<<<dim3(24, 24, 3), blk, 0, stream>>>(Wq, Wk, Wv, qkvT);
  transpose_kernel<<<dim3(24, 24), blk, 0, stream>>>(Wo, woT, EMB, EMB);
  transpose_kernel<<<dim3(96, 24), blk, 0, stream>>>(W1, w1T, EMB, FFD);
  transpose_kernel<<<dim3(24, 96), blk, 0, stream>>>(W2, w2T, FFD, EMB);

  ln_kernel<<<NTOK, blk, 0, stream>>>(x, ln1s, ln1b, h1);
  gemm_kernel<3, 128><<<dim3(18, 64), blk, 0, stream>>>(h1, qkvT, qkv, nullptr, nullptr, vT, NTOK, QKVW, EMB);
  attn_kernel<<<dim3(96, 8), blk, 0, stream>>>(qkv, vT, ctxb);
  gemm_kernel<1, 64><<<dim3(6, 128), blk, 0, stream>>>(ctxb, woT, x2, bo, x, nullptr, NTOK, EMB, EMB);
  ln_kernel<<<NTOK, blk, 0, stream>>>(x2, ln2s, ln2b, h2);
  gemm_kernel<2, 128><<<dim3(24, 64), blk, 0, stream>>>(h2, w1T, ff1, b1, nullptr, nullptr, NTOK, FFD, EMB);
  gemm_kernel<1, 64><<<dim3(6, 128), blk, 0, stream>>>(ff1, w2T, (float*)d_out, b2, x2, nullptr, NTOK, EMB, FFD);
}

// Round 7
// 233.556 us; speedup vs baseline: 1.1896x; 1.0688x over previous
//
#include <hip/hip_runtime.h>
#include <hip/hip_bf16.h>
#include <stdint.h>
#include <stddef.h>

#define EMB 768
#define FFD 3072
#define NHEAD 12
#define HD 64
#define SEQ 1024
#define NTOK 8192
#define QKVW 2304

typedef unsigned short u16;
typedef __attribute__((ext_vector_type(8))) short short8;
typedef __attribute__((ext_vector_type(4))) float f32x4;

__device__ __forceinline__ u16 f2bf(float f) {
  union { float f; uint32_t u; } w; w.f = f;
  uint32_t x = w.u + 0x7fffu + ((w.u >> 16) & 1u);
  return (u16)(x >> 16);
}

__device__ __forceinline__ uint32_t pkbf(float lo, float hi) {
  __hip_bfloat162 h = __float22bfloat162_rn(float2{lo, hi});
  union { __hip_bfloat162 h; uint32_t u; } cv; cv.h = h;
  return cv.u;
}

__device__ __forceinline__ void g2l16(const void* g, void* l) {
  __builtin_amdgcn_global_load_lds(
      (const __attribute__((address_space(1))) void*)g,
      (__attribute__((address_space(3))) void*)l, 16, 0, 0);
}

// ---------------- weight transpose: fp32 [K][N] -> bf16 [N][K] ----------------
__global__ __launch_bounds__(256)
void transpose_kernel(const float* __restrict__ in, u16* __restrict__ out, int K, int N) {
  __shared__ float tile[32][33];
  const int n0 = blockIdx.x * 32, k0 = blockIdx.y * 32;
  const int tx = threadIdx.x & 31;
  const int ty = threadIdx.x >> 5;
#pragma unroll
  for (int i = 0; i < 32; i += 8)
    tile[ty + i][tx] = in[(size_t)(k0 + ty + i) * N + n0 + tx];
  __syncthreads();
#pragma unroll
  for (int i = 0; i < 32; i += 8)
    out[(size_t)(n0 + ty + i) * K + k0 + tx] = f2bf(tile[tx][ty + i]);
}

// merged Wq/Wk/Wv transpose (768x768 each), z selects the source
__global__ __launch_bounds__(256)
void transpose_qkv_kernel(const float* __restrict__ Wq, const float* __restrict__ Wk,
                          const float* __restrict__ Wv, u16* __restrict__ out) {
  __shared__ float tile[32][33];
  const float* in = blockIdx.z == 0 ? Wq : (blockIdx.z == 1 ? Wk : Wv);
  u16* o = out + (size_t)blockIdx.z * EMB * EMB;
  const int n0 = blockIdx.x * 32, k0 = blockIdx.y * 32;
  const int tx = threadIdx.x & 31;
  const int ty = threadIdx.x >> 5;
#pragma unroll
  for (int i = 0; i < 32; i += 8)
    tile[ty + i][tx] = in[(size_t)(k0 + ty + i) * EMB + n0 + tx];
  __syncthreads();
#pragma unroll
  for (int i = 0; i < 32; i += 8)
    o[(size_t)(n0 + ty + i) * EMB + k0 + tx] = f2bf(tile[tx][ty + i]);
}

// ---------------- layernorm: fp32 row -> bf16 row ----------------
__global__ __launch_bounds__(256)
void ln_kernel(const float* __restrict__ x, const float* __restrict__ sc,
               const float* __restrict__ sh, u16* __restrict__ out) {
  const int row = blockIdx.x;
  const int tid = threadIdx.x;
  const float* xr = x + (size_t)row * EMB;
  float v0 = xr[tid], v1 = xr[tid + 256], v2 = xr[tid + 512];
  float s = v0 + v1 + v2;
  float ss = v0 * v0 + v1 * v1 + v2 * v2;
#pragma unroll
  for (int m = 1; m < 64; m <<= 1) { s += __shfl_xor(s, m, 64); ss += __shfl_xor(ss, m, 64); }
  __shared__ float red[8];
  const int wave = tid >> 6, lane = tid & 63;
  if (lane == 0) { red[wave] = s; red[wave + 4] = ss; }
  __syncthreads();
  s = red[0] + red[1] + red[2] + red[3];
  ss = red[4] + red[5] + red[6] + red[7];
  const float mean = s * (1.f / EMB);
  const float var = ss * (1.f / EMB) - mean * mean;
  const float inv = rsqrtf(var + 1e-5f);
  u16* orow = out + (size_t)row * EMB;
  orow[tid]       = f2bf((v0 - mean) * inv * sc[tid]       + sh[tid]);
  orow[tid + 256] = f2bf((v1 - mean) * inv * sc[tid + 256] + sh[tid + 256]);
  orow[tid + 512] = f2bf((v2 - mean) * inv * sc[tid + 512] + sh[tid + 512]);
}

// ---------------- bf16 GEMM: C[M,N] = A[M,K] @ BT[N,K]^T ----------------
// Round-4 single-buffered mainloop (best measured). SWAP variants compute
// with operands exchanged: mfma(bf, af) -> lane holds one M-row and 4
// consecutive N-cols per frag -> vectorized float4/uint2 epilogue.
// EPI 1 (SWAP): C f32  = acc + bias[n] + res[m*N+n]   (float4 ld/st)
// EPI 2 (SWAP): C bf16 = gelu_tanh(acc + bias[n])     (uint2 st, cvt_pk)
// EPI 3       : QKV split (cols<1536 row-major bf16; V transposed into vTp)
template <int EPI, int MT, bool SWAP>
__global__ __launch_bounds__(256)
void gemm_kernel(const u16* __restrict__ A, const u16* __restrict__ BT,
                 void* __restrict__ Cp, const float* __restrict__ bias,
                 const float* __restrict__ res, u16* __restrict__ vTp,
                 int M, int N, int K) {
  constexpr int MI = MT / 32;
  __shared__ u16 As[MT * 64];
  __shared__ u16 Bs[128 * 64];

  const int nwg = gridDim.x * gridDim.y;
  const int orig = blockIdx.y * gridDim.x + blockIdx.x;
  const int swz = (orig & 7) * (nwg >> 3) + (orig >> 3);
  const int m0 = (swz / gridDim.x) * MT;
  const int n0 = (swz % gridDim.x) * 128;

  const int tid = threadIdx.x;
  const int wave = tid >> 6, lane = tid & 63;
  const int wr = wave >> 1, wc = wave & 1;
  const int r = lane & 15, g = lane >> 4;
  const int lrow = lane >> 3;
  const int lelem = (lane & 7) * 8;

  f32x4 acc[MI][4] = {};

  const int nkt = K >> 6;
  for (int kt = 0; kt < nkt; ++kt) {
    const int k0 = kt << 6;
    if (kt) __syncthreads();
#pragma unroll
    for (int q = 0; q < MT / 32; ++q) {
      const int chunk = q * 4 + wave;
      const int row = chunk * 8 + lrow;
      const int e = lelem ^ ((row & 7) << 3);
      g2l16(A + (size_t)(m0 + row) * K + k0 + e, As + chunk * 512);
    }
#pragma unroll
    for (int q = 0; q < 4; ++q) {
      const int chunk = q * 4 + wave;
      const int row = chunk * 8 + lrow;
      const int e = lelem ^ ((row & 7) << 3);
      g2l16(BT + (size_t)(n0 + row) * K + k0 + e, Bs + chunk * 512);
    }
    __syncthreads();
#pragma unroll
    for (int kk = 0; kk < 2; ++kk) {
      short8 af[MI], bf[4];
#pragma unroll
      for (int mi = 0; mi < MI; ++mi) {
        const int row = wr * (MT / 2) + mi * 16 + r;
        af[mi] = *(const short8*)(As + row * 64 + ((kk * 32 + g * 8) ^ ((row & 7) << 3)));
      }
#pragma unroll
      for (int ni = 0; ni < 4; ++ni) {
        const int row = wc * 64 + ni * 16 + r;
        bf[ni] = *(const short8*)(Bs + row * 64 + ((kk * 32 + g * 8) ^ ((row & 7) << 3)));
      }
#pragma unroll
      for (int mi = 0; mi < MI; ++mi)
#pragma unroll
        for (int ni = 0; ni < 4; ++ni) {
          if constexpr (SWAP)
            acc[mi][ni] = __builtin_amdgcn_mfma_f32_16x16x32_bf16(bf[ni], af[mi], acc[mi][ni], 0, 0, 0);
          else
            acc[mi][ni] = __builtin_amdgcn_mfma_f32_16x16x32_bf16(af[mi], bf[ni], acc[mi][ni], 0, 0, 0);
        }
    }
  }

  if constexpr (SWAP) {
    // lane holds: m = m0+wr*(MT/2)+mi*16+r (fixed), n = n0+wc*64+ni*16+4g+j
#pragma unroll
    for (int mi = 0; mi < MI; ++mi) {
      const int m = m0 + wr * (MT / 2) + mi * 16 + r;
#pragma unroll
      for (int ni = 0; ni < 4; ++ni) {
        const int nb = n0 + wc * 64 + ni * 16 + 4 * g;
        if constexpr (EPI == 1) {
          const float4 bs = *(const float4*)(bias + nb);
          const float4 rs = *(const float4*)(res + (size_t)m * N + nb);
          float4 o;
          o.x = acc[mi][ni][0] + bs.x + rs.x;
          o.y = acc[mi][ni][1] + bs.y + rs.y;
          o.z = acc[mi][ni][2] + bs.z + rs.z;
          o.w = acc[mi][ni][3] + bs.w + rs.w;
          *(float4*)((float*)Cp + (size_t)m * N + nb) = o;
        } else {  // EPI == 2 (GELU -> bf16)
          const float4 bs = *(const float4*)(bias + nb);
          float tj[4];
#pragma unroll
          for (int j = 0; j < 4; ++j) {
            float t = acc[mi][ni][j] + (&bs.x)[j];
            float e = __expf(1.5957691216057308f * (t + 0.044715f * t * t * t));
            tj[j] = 0.5f * t * (1.f + (1.f - 2.f / (e + 1.f)));
          }
          uint2 w2;
          w2.x = pkbf(tj[0], tj[1]);
          w2.y = pkbf(tj[2], tj[3]);
          *(uint2*)((u16*)Cp + (size_t)m * N + nb) = w2;
        }
      }
    }
  } else {
    // EPI == 3: lane holds col = n0+wc*64+ni*16+r (fixed), rows rowb+0..3
#pragma unroll
    for (int mi = 0; mi < MI; ++mi)
#pragma unroll
      for (int ni = 0; ni < 4; ++ni) {
        const int rowb = m0 + wr * (MT / 2) + mi * 16 + 4 * g;
        const int col = n0 + wc * 64 + ni * 16 + r;
        u16 pk[4];
#pragma unroll
        for (int j = 0; j < 4; ++j) pk[j] = f2bf(acc[mi][ni][j]);
        if (col < 1536) {
#pragma unroll
          for (int j = 0; j < 4; ++j)
            ((u16*)Cp)[(size_t)(rowb + j) * N + col] = pk[j];
        } else {
          uint2 w2;
          w2.x = (uint32_t)pk[0] | ((uint32_t)pk[1] << 16);
          w2.y = (uint32_t)pk[2] | ((uint32_t)pk[3] << 16);
          *(uint2*)(vTp + (size_t)(col - 1536) * NTOK + rowb) = w2;
        }
      }
  }
}

// ---------------- flash attention, causal, QBLK=128, swapped-QK^T ----------------
#define CEXP 0.18033688011112042f  /* log2(e)/8 */

__global__ __launch_bounds__(256, 3)
void attn_kernel(const u16* __restrict__ qkv, const u16* __restrict__ vT,
                 u16* __restrict__ ctx) {
  const int bh = blockIdx.x;
  const int qt = blockIdx.y;
  const int b = bh / NHEAD, h = bh % NHEAD;
  const int tid = threadIdx.x;
  const int wave = tid >> 6, lane = tid & 63;
  const int r = lane & 15, g = lane >> 4;

  __shared__ u16 Kb[2][64 * 64];
  __shared__ u16 Vb[2][64 * 64];
  __shared__ u16 Pt[4][16 * 64];

  const int qw = qt * 128 + wave * 32;
  const int tok0 = b * SEQ;

  short8 aq[2][2];
#pragma unroll
  for (int qf = 0; qf < 2; ++qf) {
    const u16* qb = qkv + (size_t)(tok0 + qw + qf * 16 + r) * QKVW + h * HD;
    aq[qf][0] = *(const short8*)(qb + g * 8);
    aq[qf][1] = *(const short8*)(qb + 32 + g * 8);
  }

  float l_st[2] = {0.f, 0.f};
  f32x4 oc[2][4] = {};

  const int sr = tid >> 3;
  const int sc = (tid & 7) * 8;
  const int nt = 2 * qt + 2;

  const u16* kg = qkv + (size_t)tok0 * QKVW + EMB + h * HD;
  const u16* vg = vT + (size_t)(h * HD) * NTOK + tok0;
  const int e0 = sc ^ ((sr & 7) << 3);

  auto stage = [&](int buf, int kt) {
    const size_t koff = (size_t)kt * 64;
    u16* kb = (u16*)Kb[buf] + wave * 512;
    u16* vb = (u16*)Vb[buf] + wave * 512;
    g2l16(kg + (koff + sr) * QKVW + e0, kb);
    g2l16(kg + (koff + sr + 32) * QKVW + e0, kb + 2048);
    g2l16(vg + (size_t)sr * NTOK + koff + e0, vb);
    g2l16(vg + (size_t)(sr + 32) * NTOK + koff + e0, vb + 2048);
  };

  stage(0, 0);
  for (int kb = 0; kb < nt; ++kb) {
    __syncthreads();
    const int cur = kb & 1;
    if (kb + 1 < nt) stage(cur ^ 1, kb + 1);

    const int kv0 = kb * 64;
    if (kv0 > qw + 31) continue;

    short8 kf[4][2];
#pragma unroll
    for (int nf = 0; nf < 4; ++nf) {
      const int row = nf * 16 + r;
#pragma unroll
      for (int kk = 0; kk < 2; ++kk)
        kf[nf][kk] = *(const short8*)((char*)Kb[cur] + row * 128 +
                                      ((kk * 64 + g * 16) ^ ((row & 7) << 4)));
    }
    short8 bv[2][4];
#pragma unroll
    for (int half = 0; half < 2; ++half)
#pragma unroll
      for (int nd = 0; nd < 4; ++nd) {
        const int vr = nd * 16 + r;
        bv[half][nd] = *(const short8*)((char*)Vb[cur] + vr * 128 +
                       ((half * 64 + g * 16) ^ ((vr & 7) << 4)));
      }

#pragma unroll
    for (int qf = 0; qf < 2; ++qf) {
      f32x4 st[4];
#pragma unroll
      for (int nf = 0; nf < 4; ++nf) {
        f32x4 z = {};
        z = __builtin_amdgcn_mfma_f32_16x16x32_bf16(kf[nf][0], aq[qf][0], z, 0, 0, 0);
        z = __builtin_amdgcn_mfma_f32_16x16x32_bf16(kf[nf][1], aq[qf][1], z, 0, 0, 0);
        st[nf] = z;
      }
      if (kv0 + 63 > qw + qf * 16) {
        const int qg = qw + qf * 16 + r;
#pragma unroll
        for (int nf = 0; nf < 4; ++nf)
#pragma unroll
          for (int j = 0; j < 4; ++j)
            if (kv0 + nf * 16 + 4 * g + j > qg) st[nf][j] = -3e38f;
      }
      float p[4][4];
      float ps = 0.f;
#pragma unroll
      for (int nf = 0; nf < 4; ++nf)
#pragma unroll
        for (int j = 0; j < 4; ++j) {
          const float pe = exp2f(st[nf][j] * CEXP);
          p[nf][j] = pe;
          ps += pe;
        }
      ps += __shfl_xor(ps, 16);
      ps += __shfl_xor(ps, 32);
      l_st[qf] += ps;

      u16* Pw = (u16*)Pt[wave];
#pragma unroll
      for (int nf = 0; nf < 4; ++nf) {
        uint2 w2;
        w2.x = pkbf(p[nf][0], p[nf][1]);
        w2.y = pkbf(p[nf][2], p[nf][3]);
        *(uint2*)((char*)Pw + r * 128 + ((nf * 32 + g * 8) ^ ((r & 7) << 4))) = w2;
      }
#pragma unroll
      for (int half = 0; half < 2; ++half) {
        short8 pa = *(const short8*)((char*)Pw + r * 128 +
                                     ((half * 64 + g * 16) ^ ((r & 7) << 4)));
#pragma unroll
        for (int nd = 0; nd < 4; ++nd)
          oc[qf][nd] = __builtin_amdgcn_mfma_f32_16x16x32_bf16(pa, bv[half][nd], oc[qf][nd], 0, 0, 0);
      }
    }
  }

#pragma unroll
  for (int qf = 0; qf < 2; ++qf) {
    const float rl = 1.f / l_st[qf];
#pragma unroll
    for (int j = 0; j < 4; ++j) {
      const float rj = __shfl(rl, 4 * g + j, 16);
      const size_t row = (size_t)tok0 + qw + qf * 16 + 4 * g + j;
#pragma unroll
      for (int nd = 0; nd < 4; ++nd)
        ctx[row * EMB + h * HD + nd * 16 + r] = f2bf(oc[qf][nd][j] * rj);
    }
  }
}

extern "C" void kernel_launch(void* const* d_in, const int* in_sizes, int n_in,
                              void* d_out, int out_size, void* d_ws, size_t ws_size,
                              hipStream_t stream) {
  const float* x    = (const float*)d_in[0];
  const float* Wq   = (const float*)d_in[1];
  const float* Wk   = (const float*)d_in[2];
  const float* Wv   = (const float*)d_in[3];
  const float* Wo   = (const float*)d_in[4];
  const float* bo   = (const float*)d_in[5];
  const float* W1   = (const float*)d_in[6];
  const float* b1   = (const float*)d_in[7];
  const float* W2   = (const float*)d_in[8];
  const float* b2   = (const float*)d_in[9];
  const float* ln1s = (const float*)d_in[10];
  const float* ln1b = (const float*)d_in[11];
  const float* ln2s = (const float*)d_in[12];
  const float* ln2b = (const float*)d_in[13];

  char* p = (char*)d_ws;
  u16* qkvT = (u16*)p; p += (size_t)QKVW * EMB * 2;
  u16* woT  = (u16*)p; p += (size_t)EMB * EMB * 2;
  u16* w1T  = (u16*)p; p += (size_t)FFD * EMB * 2;
  u16* w2T  = (u16*)p; p += (size_t)EMB * FFD * 2;
  u16* h1   = (u16*)p; p += (size_t)NTOK * EMB * 2;
  u16* qkv  = (u16*)p; p += (size_t)NTOK * QKVW * 2;
  float* x2 = (float*)p; p += (size_t)NTOK * EMB * 4;
  u16* ff1  = (u16*)p; p += (size_t)NTOK * FFD * 2;
  u16* ctxb = h1;        // h1 dead after QKV GEMM
  u16* h2   = qkv;       // qkv dead after attention
  u16* vT   = ff1;       // vT lives [QKV GEMM, attn); ff1 lives [FF1 GEMM, end)

  if (ws_size < (size_t)(p - (char*)d_ws)) return;

  dim3 blk(256);
  transpose_qkv_kernel<<<dim3(24, 24, 3), blk, 0, stream>>>(Wq, Wk, Wv, qkvT);
  transpose_kernel<<<dim3(24, 24), blk, 0, stream>>>(Wo, woT, EMB, EMB);
  transpose_kernel<<<dim3(96, 24), blk, 0, stream>>>(W1, w1T, EMB, FFD);
  transpose_kernel<<<dim3(24, 96), blk, 0, stream>>>(W2, w2T, FFD, EMB);

  ln_kernel<<<NTOK, blk, 0, stream>>>(x, ln1s, ln1b, h1);
  gemm_kernel<3, 128, false><<<dim3(18, 64), blk, 0, stream>>>(h1, qkvT, qkv, nullptr, nullptr, vT, NTOK, QKVW, EMB);
  attn_kernel<<<dim3(96, 8), blk, 0, stream>>>(qkv, vT, ctxb);
  gemm_kernel<1, 64, true><<<dim3(6, 128), blk, 0, stream>>>(ctxb, woT, x2, bo, x, nullptr, NTOK, EMB, EMB);
  ln_kernel<<<NTOK, blk, 0, stream>>>(x2, ln2s, ln2b, h2);
  gemm_kernel<2, 128, true><<<dim3(24, 64), blk, 0, stream>>>(h2, w1T, ff1, b1, nullptr, nullptr, NTOK, FFD, EMB);
  gemm_kernel<1, 64, true><<<dim3(6, 128), blk, 0, stream>>>(ff1, w2T, (float*)d_out, b2, x2, nullptr, NTOK, EMB, FFD);
}